// Round 1
// baseline (432.344 us; speedup 1.0000x reference)
//
#include <hip/hip_runtime.h>
#include <hip/hip_bf16.h>

#define BB 8
#define SS 1024
#define DD 1024
#define HH 16
#define DK 64
#define MM (BB*SS)   // 8192

typedef __attribute__((ext_vector_type(8))) short bf16x8;
typedef __attribute__((ext_vector_type(4))) float f32x4;

static __device__ __forceinline__ short f2bf(float f) {
    union { float f; unsigned u; } x; x.f = f;
    unsigned r = x.u + 0x7fffu + ((x.u >> 16) & 1u);
    return (short)(r >> 16);
}

// ---------------- Kernel 1: W[K][N] fp32 -> Wt[N][K] bf16 (x3) ----------------
__global__ void wtrans_kernel(const float* __restrict__ w0, const float* __restrict__ w1,
                              const float* __restrict__ w2, short* __restrict__ wt) {
    __shared__ short t[32][33];
    int p = blockIdx.z;
    const float* wsrc = p == 0 ? w0 : (p == 1 ? w1 : w2);
    short* dst = wt + (size_t)p * DD * DD;
    int k0 = blockIdx.y * 32, n0 = blockIdx.x * 32;
    int tx = threadIdx.x & 31, ty = threadIdx.x >> 5;
    #pragma unroll
    for (int i = 0; i < 4; ++i) {
        int k = ty + 8 * i;
        t[k][tx] = f2bf(wsrc[(size_t)(k0 + k) * DD + n0 + tx]);
    }
    __syncthreads();
    #pragma unroll
    for (int i = 0; i < 4; ++i) {
        int n = ty + 8 * i;
        dst[(size_t)(n0 + n) * DD + k0 + tx] = t[tx][n];
    }
}

// ---------------- Kernel 2: QKV projection GEMM (bf16 MFMA) ----------------
// Y = X @ W + b ; X fp32 [M][K], Wt bf16 [N][K], out bf16 in [B][H][S][dk]
#define BM 128
#define BN 128
#define BK 64
#define LDT 72   // LDS row stride in shorts (144 B, 16B-multiple, 2-way max aliasing)

__launch_bounds__(256, 2)
__global__ void qkvproj_kernel(const float* __restrict__ xq, const float* __restrict__ xk,
                               const float* __restrict__ xv,
                               const short* __restrict__ wt,
                               const float* __restrict__ bq, const float* __restrict__ bk,
                               const float* __restrict__ bv,
                               short* __restrict__ qh, short* __restrict__ kh,
                               short* __restrict__ vh) {
    __shared__ short As[BM * LDT];
    __shared__ short Bs[BN * LDT];
    int p = blockIdx.z;
    const float* X = p == 0 ? xq : (p == 1 ? xk : xv);
    const short* Wt = wt + (size_t)p * DD * DD;
    const float* bias = p == 0 ? bq : (p == 1 ? bk : bv);
    short* out = p == 0 ? qh : (p == 1 ? kh : vh);
    int m0 = blockIdx.y * BM, n0 = blockIdx.x * BN;
    int t = threadIdx.x;
    int l = t & 63, w = t >> 6;
    int wm = (w >> 1) * 64, wn = (w & 1) * 64;
    int lg = l >> 4, lr = l & 15;

    f32x4 acc[4][4];
    #pragma unroll
    for (int mi = 0; mi < 4; ++mi)
        #pragma unroll
        for (int ni = 0; ni < 4; ++ni) acc[mi][ni] = 0.f;

    for (int k0 = 0; k0 < DD; k0 += BK) {
        __syncthreads();
        // stage A: fp32 -> bf16, 128x64
        #pragma unroll
        for (int i = 0; i < 4; ++i) {
            int c = t + 256 * i;
            int row = c >> 3, kc = (c & 7) * 8;
            const float* src = X + (size_t)(m0 + row) * DD + k0 + kc;
            f32x4 f0 = *(const f32x4*)(src);
            f32x4 f1 = *(const f32x4*)(src + 4);
            bf16x8 pk;
            pk[0] = f2bf(f0[0]); pk[1] = f2bf(f0[1]); pk[2] = f2bf(f0[2]); pk[3] = f2bf(f0[3]);
            pk[4] = f2bf(f1[0]); pk[5] = f2bf(f1[1]); pk[6] = f2bf(f1[2]); pk[7] = f2bf(f1[3]);
            *(bf16x8*)(&As[row * LDT + kc]) = pk;
        }
        // stage B: bf16 copy, 128x64
        #pragma unroll
        for (int i = 0; i < 4; ++i) {
            int c = t + 256 * i;
            int row = c >> 3, kc = (c & 7) * 8;
            *(bf16x8*)(&Bs[row * LDT + kc]) =
                *(const bf16x8*)(Wt + (size_t)(n0 + row) * DD + k0 + kc);
        }
        __syncthreads();
        #pragma unroll
        for (int kk = 0; kk < 2; ++kk) {
            bf16x8 a[4], b[4];
            #pragma unroll
            for (int mi = 0; mi < 4; ++mi)
                a[mi] = *(const bf16x8*)(&As[(wm + mi * 16 + lr) * LDT + kk * 32 + lg * 8]);
            #pragma unroll
            for (int ni = 0; ni < 4; ++ni)
                b[ni] = *(const bf16x8*)(&Bs[(wn + ni * 16 + lr) * LDT + kk * 32 + lg * 8]);
            #pragma unroll
            for (int mi = 0; mi < 4; ++mi)
                #pragma unroll
                for (int ni = 0; ni < 4; ++ni)
                    acc[mi][ni] = __builtin_amdgcn_mfma_f32_16x16x32_bf16(a[mi], b[ni], acc[mi][ni], 0, 0, 0);
        }
    }
    // epilogue: bias + cast + head-split store [B][H][S][dk]
    #pragma unroll
    for (int ni = 0; ni < 4; ++ni) {
        int n = n0 + wn + ni * 16 + lr;
        float bvv = bias[n];
        int h = n >> 6, dd = n & 63;
        #pragma unroll
        for (int mi = 0; mi < 4; ++mi) {
            int mbase = m0 + wm + mi * 16 + lg * 4;
            #pragma unroll
            for (int r = 0; r < 4; ++r) {
                int m = mbase + r;
                int b_ = m >> 10, s_ = m & 1023;
                out[(((size_t)(b_ * HH + h) * SS + s_) * DK) + dd] = f2bf(acc[mi][ni][r] + bvv);
            }
        }
    }
}

// ---------------- Kernel 3: Vh[bh][s][d] -> Vt[bh][d][s] ----------------
__global__ void vtrans_kernel(const short* __restrict__ vh, short* __restrict__ vt) {
    __shared__ short tile[64 * 72];
    int bh = blockIdx.y;
    int s0 = blockIdx.x * 64;
    int t = threadIdx.x;
    #pragma unroll
    for (int i = 0; i < 2; ++i) {
        int c = t + 256 * i;
        int row = c >> 3, dc = (c & 7) * 8;
        *(bf16x8*)&tile[row * 72 + dc] =
            *(const bf16x8*)(vh + ((size_t)bh * SS + s0 + row) * DK + dc);
    }
    __syncthreads();
    #pragma unroll
    for (int i = 0; i < 2; ++i) {
        int c = t + 256 * i;
        int dr = c >> 3, scc = (c & 7) * 8;
        bf16x8 vv;
        #pragma unroll
        for (int j = 0; j < 8; ++j) vv[j] = tile[(scc + j) * 72 + dr];
        *(bf16x8*)(vt + ((size_t)bh * DK + dr) * SS + s0 + scc) = vv;
    }
}

// ---------------- Kernel 4: flash attention ----------------
// 1 block = (bh, 64 q rows); 4 waves x 16 q-rows; KVBLK=64; online softmax
__launch_bounds__(256, 2)
__global__ void attn_kernel(const short* __restrict__ qh, const short* __restrict__ kh,
                            const short* __restrict__ vt, float* __restrict__ out) {
    __shared__ short plds[4][16 * 72];
    int bh = blockIdx.y;
    int q0 = blockIdx.x * 64;
    int t = threadIdx.x, l = t & 63, w = t >> 6;
    int lg = l >> 4, lr = l & 15;
    const short* Q = qh + (size_t)bh * SS * DK;
    const short* K = kh + (size_t)bh * SS * DK;
    const short* V = vt + (size_t)bh * DK * SS;

    bf16x8 aq0 = *(const bf16x8*)(Q + (size_t)(q0 + w * 16 + lr) * DK + lg * 8);
    bf16x8 aq1 = *(const bf16x8*)(Q + (size_t)(q0 + w * 16 + lr) * DK + 32 + lg * 8);

    float m_r[4], l_r[4];
    f32x4 o[4];
    #pragma unroll
    for (int r = 0; r < 4; ++r) { m_r[r] = -1e30f; l_r[r] = 0.f; }
    #pragma unroll
    for (int dt = 0; dt < 4; ++dt) o[dt] = 0.f;

    for (int kv0 = 0; kv0 < SS; kv0 += 64) {
        f32x4 sc[4];
        #pragma unroll
        for (int ct = 0; ct < 4; ++ct) {
            const short* kp = K + (size_t)(kv0 + ct * 16 + lr) * DK + lg * 8;
            bf16x8 bk0 = *(const bf16x8*)(kp);
            bf16x8 bk1 = *(const bf16x8*)(kp + 32);
            f32x4 z = 0.f;
            z = __builtin_amdgcn_mfma_f32_16x16x32_bf16(aq0, bk0, z, 0, 0, 0);
            z = __builtin_amdgcn_mfma_f32_16x16x32_bf16(aq1, bk1, z, 0, 0, 0);
            sc[ct] = z;
        }
        float p[4][4], tm[4];
        #pragma unroll
        for (int r = 0; r < 4; ++r) {
            float a = sc[0][r] * 0.125f, b2 = sc[1][r] * 0.125f;
            float c2 = sc[2][r] * 0.125f, d2 = sc[3][r] * 0.125f;
            p[0][r] = a; p[1][r] = b2; p[2][r] = c2; p[3][r] = d2;
            tm[r] = fmaxf(fmaxf(a, b2), fmaxf(c2, d2));
        }
        #pragma unroll
        for (int mask = 1; mask < 16; mask <<= 1)
            #pragma unroll
            for (int r = 0; r < 4; ++r) tm[r] = fmaxf(tm[r], __shfl_xor(tm[r], mask, 64));
        float alpha[4], rs[4];
        #pragma unroll
        for (int r = 0; r < 4; ++r) {
            float mn = fmaxf(m_r[r], tm[r]);
            alpha[r] = __expf(m_r[r] - mn);
            m_r[r] = mn;
            float e0 = __expf(p[0][r] - mn), e1 = __expf(p[1][r] - mn);
            float e2 = __expf(p[2][r] - mn), e3 = __expf(p[3][r] - mn);
            p[0][r] = e0; p[1][r] = e1; p[2][r] = e2; p[3][r] = e3;
            rs[r] = (e0 + e1) + (e2 + e3);
        }
        #pragma unroll
        for (int mask = 1; mask < 16; mask <<= 1)
            #pragma unroll
            for (int r = 0; r < 4; ++r) rs[r] += __shfl_xor(rs[r], mask, 64);
        #pragma unroll
        for (int r = 0; r < 4; ++r) l_r[r] = l_r[r] * alpha[r] + rs[r];
        #pragma unroll
        for (int dt = 0; dt < 4; ++dt)
            #pragma unroll
            for (int r = 0; r < 4; ++r) o[dt][r] *= alpha[r];
        // P (D-frag layout) -> LDS -> A-frag layout
        #pragma unroll
        for (int ct = 0; ct < 4; ++ct)
            #pragma unroll
            for (int r = 0; r < 4; ++r)
                plds[w][(lg * 4 + r) * 72 + ct * 16 + lr] = f2bf(p[ct][r]);
        __syncthreads();
        bf16x8 pa0 = *(const bf16x8*)&plds[w][lr * 72 + lg * 8];
        bf16x8 pa1 = *(const bf16x8*)&plds[w][lr * 72 + 32 + lg * 8];
        #pragma unroll
        for (int dt = 0; dt < 4; ++dt) {
            const short* vp = V + (size_t)(dt * 16 + lr) * SS + kv0 + lg * 8;
            bf16x8 bv0 = *(const bf16x8*)(vp);
            bf16x8 bv1 = *(const bf16x8*)(vp + 32);
            o[dt] = __builtin_amdgcn_mfma_f32_16x16x32_bf16(pa0, bv0, o[dt], 0, 0, 0);
            o[dt] = __builtin_amdgcn_mfma_f32_16x16x32_bf16(pa1, bv1, o[dt], 0, 0, 0);
        }
        __syncthreads();
    }
    int b_ = bh >> 4, h_ = bh & 15;
    #pragma unroll
    for (int r = 0; r < 4; ++r) {
        float inv = 1.0f / l_r[r];
        int srow = q0 + w * 16 + lg * 4 + r;
        float* op = out + ((size_t)(b_ * SS + srow)) * DD + h_ * DK;
        #pragma unroll
        for (int dt = 0; dt < 4; ++dt)
            op[dt * 16 + lr] = o[dt][r] * inv;
    }
}

extern "C" void kernel_launch(void* const* d_in, const int* in_sizes, int n_in,
                              void* d_out, int out_size, void* d_ws, size_t ws_size,
                              hipStream_t stream) {
    const float* q  = (const float*)d_in[0];
    const float* k  = (const float*)d_in[1];
    const float* v  = (const float*)d_in[2];
    const float* wq = (const float*)d_in[3];
    const float* bq = (const float*)d_in[4];
    const float* wk = (const float*)d_in[5];
    const float* bk = (const float*)d_in[6];
    const float* wv = (const float*)d_in[7];
    const float* bv = (const float*)d_in[8];
    float* out = (float*)d_out;

    char* ws = (char*)d_ws;
    const size_t SZ = (size_t)BB * HH * SS * DK * sizeof(short); // 16 MB
    short* Qh = (short*)(ws);
    short* Kh = (short*)(ws + SZ);
    short* Vh = (short*)(ws + 2 * SZ);
    short* Vt = (short*)(ws + 3 * SZ);
    short* Wt = (short*)(ws + 4 * SZ);  // 3 x 2 MB

    wtrans_kernel<<<dim3(32, 32, 3), 256, 0, stream>>>(wq, wk, wv, Wt);
    qkvproj_kernel<<<dim3(8, 64, 3), 256, 0, stream>>>(q, k, v, Wt, bq, bk, bv, Qh, Kh, Vh);
    vtrans_kernel<<<dim3(16, 128), 256, 0, stream>>>(Vh, Vt);
    attn_kernel<<<dim3(16, 128), 256, 0, stream>>>(Qh, Kh, Vt, out);
}

// Round 2
// 333.966 us; speedup vs baseline: 1.2946x; 1.2946x over previous
//
#include <hip/hip_runtime.h>
#include <hip/hip_bf16.h>

#define BB 8
#define SS 1024
#define DD 1024
#define HH 16
#define DK 64
#define MM (BB*SS)   // 8192

typedef __attribute__((ext_vector_type(8))) short bf16x8;
typedef __attribute__((ext_vector_type(4))) float f32x4;

// 0.125 (1/sqrt(dk)) * log2(e): fold attention scale + exp->exp2 into Q proj
#define QSCALE 0.18033688011112042f

static __device__ __forceinline__ short f2bf(float f) {
    union { float f; unsigned u; } x; x.f = f;
    unsigned r = x.u + 0x7fffu + ((x.u >> 16) & 1u);
    return (short)(r >> 16);
}

#define GLOAD16(g, s) __builtin_amdgcn_global_load_lds( \
    (const __attribute__((address_space(1))) void*)(g), \
    (__attribute__((address_space(3))) void*)(s), 16, 0, 0)

// ---------------- Kernel 1: W[K][N] fp32 -> Wt[N][K] bf16 (x3) ----------------
__global__ void wtrans_kernel(const float* __restrict__ w0, const float* __restrict__ w1,
                              const float* __restrict__ w2, short* __restrict__ wt) {
    __shared__ short t[32][33];
    int p = blockIdx.z;
    const float* wsrc = p == 0 ? w0 : (p == 1 ? w1 : w2);
    short* dst = wt + (size_t)p * DD * DD;
    int k0 = blockIdx.y * 32, n0 = blockIdx.x * 32;
    int tx = threadIdx.x & 31, ty = threadIdx.x >> 5;
    #pragma unroll
    for (int i = 0; i < 4; ++i) {
        int k = ty + 8 * i;
        t[k][tx] = f2bf(wsrc[(size_t)(k0 + k) * DD + n0 + tx]);
    }
    __syncthreads();
    #pragma unroll
    for (int i = 0; i < 4; ++i) {
        int n = ty + 8 * i;
        dst[(size_t)(n0 + n) * DD + k0 + tx] = t[tx][n];
    }
}

// ---------------- Kernel 1b: X fp32 -> bf16 (for global_load_lds A path) ------
__global__ void xcast_kernel(const float* __restrict__ xq, const float* __restrict__ xk,
                             const float* __restrict__ xv, short* __restrict__ xbf) {
    int z = blockIdx.y;
    const float* src = z == 0 ? xq : (z == 1 ? xk : xv);
    size_t i = ((size_t)blockIdx.x * 256 + threadIdx.x) * 8;
    f32x4 a = *(const f32x4*)(src + i);
    f32x4 b = *(const f32x4*)(src + i + 4);
    bf16x8 pk;
    pk[0] = f2bf(a[0]); pk[1] = f2bf(a[1]); pk[2] = f2bf(a[2]); pk[3] = f2bf(a[3]);
    pk[4] = f2bf(b[0]); pk[5] = f2bf(b[1]); pk[6] = f2bf(b[2]); pk[7] = f2bf(b[3]);
    *(bf16x8*)(xbf + (size_t)z * MM * DD + i) = pk;
}

// ---------------- Kernel 2: QKV projection GEMM (bf16 MFMA) ----------------
// Y = X @ W + b ; out bf16 in [B][H][S][dk]. LDS tiles 128x64 bf16, unpadded,
// XOR-swizzled on 16B units: LDS(row, seg) holds global(row, seg ^ (row&7)).
#define BM 128
#define BN 128
#define BK 64

template<int ABF16>
__launch_bounds__(256, 2)
__global__ void qkvproj_kernel(const float* __restrict__ xq, const float* __restrict__ xk,
                               const float* __restrict__ xv,
                               const short* __restrict__ xbf,
                               const short* __restrict__ wt,
                               const float* __restrict__ bq, const float* __restrict__ bk,
                               const float* __restrict__ bv,
                               short* __restrict__ qh, short* __restrict__ kh,
                               short* __restrict__ vh) {
    __shared__ short As[BM * 64];
    __shared__ short Bs[BN * 64];
    int p = blockIdx.z;
    const float* X = p == 0 ? xq : (p == 1 ? xk : xv);
    const short* Wt = wt + (size_t)p * DD * DD;
    const float* bias = p == 0 ? bq : (p == 1 ? bk : bv);
    short* out = p == 0 ? qh : (p == 1 ? kh : vh);
    int m0 = blockIdx.y * BM, n0 = blockIdx.x * BN;
    int t = threadIdx.x;
    int l = t & 63, w = t >> 6;
    int wm = (w >> 1) * 64, wn = (w & 1) * 64;
    int lg = l >> 4, lr = l & 15;
    int rx = lr & 7;

    f32x4 acc[4][4];
    #pragma unroll
    for (int mi = 0; mi < 4; ++mi)
        #pragma unroll
        for (int ni = 0; ni < 4; ++ni) acc[mi][ni] = 0.f;

    for (int k0 = 0; k0 < DD; k0 += BK) {
        __syncthreads();
        // stage A
        if constexpr (ABF16) {
            const short* Xb = xbf + (size_t)p * MM * DD;
            #pragma unroll
            for (int j = 0; j < 4; ++j) {
                int chunk = j * 256 + t;
                int row = chunk >> 3, seg = chunk & 7;
                const short* src = Xb + (size_t)(m0 + row) * DD + k0 + ((seg ^ (row & 7)) * 8);
                GLOAD16(src, &As[(j * 256 + w * 64) * 8]);
            }
        } else {
            #pragma unroll
            for (int i = 0; i < 4; ++i) {
                int c = t + 256 * i;
                int row = c >> 3, seg = c & 7;
                const float* src = X + (size_t)(m0 + row) * DD + k0 + seg * 8;
                f32x4 f0 = *(const f32x4*)(src);
                f32x4 f1 = *(const f32x4*)(src + 4);
                bf16x8 pk;
                pk[0] = f2bf(f0[0]); pk[1] = f2bf(f0[1]); pk[2] = f2bf(f0[2]); pk[3] = f2bf(f0[3]);
                pk[4] = f2bf(f1[0]); pk[5] = f2bf(f1[1]); pk[6] = f2bf(f1[2]); pk[7] = f2bf(f1[3]);
                *(bf16x8*)(&As[row * 64 + ((seg ^ (row & 7)) * 8)]) = pk;
            }
        }
        // stage B via global_load_lds (source pre-permuted so linear LDS = swizzled)
        #pragma unroll
        for (int j = 0; j < 4; ++j) {
            int chunk = j * 256 + t;
            int row = chunk >> 3, seg = chunk & 7;
            const short* src = Wt + (size_t)(n0 + row) * DD + k0 + ((seg ^ (row & 7)) * 8);
            GLOAD16(src, &Bs[(j * 256 + w * 64) * 8]);
        }
        __syncthreads();
        #pragma unroll
        for (int kk = 0; kk < 2; ++kk) {
            bf16x8 a[4], b[4];
            #pragma unroll
            for (int mi = 0; mi < 4; ++mi)
                a[mi] = *(const bf16x8*)(&As[(wm + mi * 16 + lr) * 64 + (((kk * 4 + lg) ^ rx) * 8)]);
            #pragma unroll
            for (int ni = 0; ni < 4; ++ni)
                b[ni] = *(const bf16x8*)(&Bs[(wn + ni * 16 + lr) * 64 + (((kk * 4 + lg) ^ rx) * 8)]);
            #pragma unroll
            for (int mi = 0; mi < 4; ++mi)
                #pragma unroll
                for (int ni = 0; ni < 4; ++ni)
                    acc[mi][ni] = __builtin_amdgcn_mfma_f32_16x16x32_bf16(a[mi], b[ni], acc[mi][ni], 0, 0, 0);
        }
    }
    // epilogue: bias + (Q only: fold softmax scale*log2e) + cast + head-split store
    float osc = (p == 0) ? QSCALE : 1.0f;
    #pragma unroll
    for (int ni = 0; ni < 4; ++ni) {
        int n = n0 + wn + ni * 16 + lr;
        float bvv = bias[n];
        int h = n >> 6, dd = n & 63;
        #pragma unroll
        for (int mi = 0; mi < 4; ++mi) {
            int mbase = m0 + wm + mi * 16 + lg * 4;
            #pragma unroll
            for (int r = 0; r < 4; ++r) {
                int m = mbase + r;
                int b_ = m >> 10, s_ = m & 1023;
                out[(((size_t)(b_ * HH + h) * SS + s_) * DK) + dd] = f2bf((acc[mi][ni][r] + bvv) * osc);
            }
        }
    }
}

// ---------------- Kernel 3: Vh[bh][s][d] -> Vt[bh][d][s] ----------------
__global__ void vtrans_kernel(const short* __restrict__ vh, short* __restrict__ vt) {
    __shared__ short tile[64 * 72];
    int bh = blockIdx.y;
    int s0 = blockIdx.x * 64;
    int t = threadIdx.x;
    #pragma unroll
    for (int i = 0; i < 2; ++i) {
        int c = t + 256 * i;
        int row = c >> 3, dc = (c & 7) * 8;
        *(bf16x8*)&tile[row * 72 + dc] =
            *(const bf16x8*)(vh + ((size_t)bh * SS + s0 + row) * DK + dc);
    }
    __syncthreads();
    #pragma unroll
    for (int i = 0; i < 2; ++i) {
        int c = t + 256 * i;
        int dr = c >> 3, scc = (c & 7) * 8;
        bf16x8 vv;
        #pragma unroll
        for (int j = 0; j < 8; ++j) vv[j] = tile[(scc + j) * 72 + dr];
        *(bf16x8*)(vt + ((size_t)bh * DK + dr) * SS + s0 + scc) = vv;
    }
}

// ---------------- Kernel 4: flash attention ----------------
// 1 block = (bh, 64 q rows); 4 independent waves x 16 q-rows; KVBLK=64.
// No block barriers (plds is per-wave). Scores arrive pre-scaled by
// 0.125*log2e -> softmax in exp2 domain. XCD-swizzled blockIdx for K/V L2 reuse.
__launch_bounds__(256, 3)
__global__ void attn_kernel(const short* __restrict__ qh, const short* __restrict__ kh,
                            const short* __restrict__ vt, float* __restrict__ out) {
    __shared__ short plds[4][16 * 72];
    int lin = blockIdx.y * 16 + blockIdx.x;        // 2048 blocks, 2048%8==0
    int swz = (lin & 7) * 256 + (lin >> 3);        // bijective XCD chunking
    int bh = swz >> 4;
    int q0 = (swz & 15) * 64;
    int t = threadIdx.x, l = t & 63, w = t >> 6;
    int lg = l >> 4, lr = l & 15;
    const short* Q = qh + (size_t)bh * SS * DK;
    const short* K = kh + (size_t)bh * SS * DK;
    const short* V = vt + (size_t)bh * DK * SS;

    bf16x8 aq0 = *(const bf16x8*)(Q + (size_t)(q0 + w * 16 + lr) * DK + lg * 8);
    bf16x8 aq1 = *(const bf16x8*)(Q + (size_t)(q0 + w * 16 + lr) * DK + 32 + lg * 8);

    float m_r[4], l_r[4];
    f32x4 o[4];
    #pragma unroll
    for (int r = 0; r < 4; ++r) { m_r[r] = -1e30f; l_r[r] = 0.f; }
    #pragma unroll
    for (int dt = 0; dt < 4; ++dt) o[dt] = 0.f;

    for (int kv0 = 0; kv0 < SS; kv0 += 64) {
        f32x4 sc[4];
        __builtin_amdgcn_s_setprio(1);
        #pragma unroll
        for (int ct = 0; ct < 4; ++ct) {
            const short* kp = K + (size_t)(kv0 + ct * 16 + lr) * DK + lg * 8;
            bf16x8 bk0 = *(const bf16x8*)(kp);
            bf16x8 bk1 = *(const bf16x8*)(kp + 32);
            f32x4 z = 0.f;
            z = __builtin_amdgcn_mfma_f32_16x16x32_bf16(aq0, bk0, z, 0, 0, 0);
            z = __builtin_amdgcn_mfma_f32_16x16x32_bf16(aq1, bk1, z, 0, 0, 0);
            sc[ct] = z;
        }
        __builtin_amdgcn_s_setprio(0);
        // hoist V loads (independent of softmax; HBM/L2 latency hides under VALU)
        bf16x8 bv0[4], bv1[4];
        #pragma unroll
        for (int dt = 0; dt < 4; ++dt) {
            const short* vp = V + (size_t)(dt * 16 + lr) * SS + kv0 + lg * 8;
            bv0[dt] = *(const bf16x8*)(vp);
            bv1[dt] = *(const bf16x8*)(vp + 32);
        }
        // row max over ct (in-lane) and lr (16-lane shuffle)
        float tm[4];
        #pragma unroll
        for (int r = 0; r < 4; ++r)
            tm[r] = fmaxf(fmaxf(sc[0][r], sc[1][r]), fmaxf(sc[2][r], sc[3][r]));
        #pragma unroll
        for (int mask = 1; mask < 16; mask <<= 1)
            #pragma unroll
            for (int r = 0; r < 4; ++r) tm[r] = fmaxf(tm[r], __shfl_xor(tm[r], mask, 64));
        // defer-max: skip rescale when no row max grew (wave-uniform branch)
        int grow = 0;
        #pragma unroll
        for (int r = 0; r < 4; ++r) grow |= (tm[r] > m_r[r]) ? 1 : 0;
        if (__any(grow)) {
            #pragma unroll
            for (int r = 0; r < 4; ++r) {
                float mn = fmaxf(m_r[r], tm[r]);
                float alpha = exp2f(m_r[r] - mn);
                m_r[r] = mn;
                l_r[r] *= alpha;
                o[0][r] *= alpha; o[1][r] *= alpha; o[2][r] *= alpha; o[3][r] *= alpha;
            }
        }
        float p[4][4], rs[4];
        #pragma unroll
        for (int r = 0; r < 4; ++r) {
            p[0][r] = exp2f(sc[0][r] - m_r[r]);
            p[1][r] = exp2f(sc[1][r] - m_r[r]);
            p[2][r] = exp2f(sc[2][r] - m_r[r]);
            p[3][r] = exp2f(sc[3][r] - m_r[r]);
            rs[r] = (p[0][r] + p[1][r]) + (p[2][r] + p[3][r]);
        }
        #pragma unroll
        for (int mask = 1; mask < 16; mask <<= 1)
            #pragma unroll
            for (int r = 0; r < 4; ++r) rs[r] += __shfl_xor(rs[r], mask, 64);
        #pragma unroll
        for (int r = 0; r < 4; ++r) l_r[r] += rs[r];
        // P (D-frag) -> per-wave LDS -> A-frag (same-wave dep, no barrier needed)
        #pragma unroll
        for (int ct = 0; ct < 4; ++ct)
            #pragma unroll
            for (int r = 0; r < 4; ++r)
                plds[w][(lg * 4 + r) * 72 + ct * 16 + lr] = f2bf(p[ct][r]);
        bf16x8 pa0 = *(const bf16x8*)&plds[w][lr * 72 + lg * 8];
        bf16x8 pa1 = *(const bf16x8*)&plds[w][lr * 72 + 32 + lg * 8];
        __builtin_amdgcn_s_setprio(1);
        #pragma unroll
        for (int dt = 0; dt < 4; ++dt) {
            o[dt] = __builtin_amdgcn_mfma_f32_16x16x32_bf16(pa0, bv0[dt], o[dt], 0, 0, 0);
            o[dt] = __builtin_amdgcn_mfma_f32_16x16x32_bf16(pa1, bv1[dt], o[dt], 0, 0, 0);
        }
        __builtin_amdgcn_s_setprio(0);
    }
    int b_ = bh >> 4, h_ = bh & 15;
    #pragma unroll
    for (int r = 0; r < 4; ++r) {
        float inv = 1.0f / l_r[r];
        int srow = q0 + w * 16 + lg * 4 + r;
        float* op = out + ((size_t)(b_ * SS + srow)) * DD + h_ * DK;
        #pragma unroll
        for (int dt = 0; dt < 4; ++dt)
            op[dt * 16 + lr] = o[dt][r] * inv;
    }
}

extern "C" void kernel_launch(void* const* d_in, const int* in_sizes, int n_in,
                              void* d_out, int out_size, void* d_ws, size_t ws_size,
                              hipStream_t stream) {
    const float* q  = (const float*)d_in[0];
    const float* k  = (const float*)d_in[1];
    const float* v  = (const float*)d_in[2];
    const float* wq = (const float*)d_in[3];
    const float* bq = (const float*)d_in[4];
    const float* wk = (const float*)d_in[5];
    const float* bk = (const float*)d_in[6];
    const float* wv = (const float*)d_in[7];
    const float* bv = (const float*)d_in[8];
    float* out = (float*)d_out;

    char* ws = (char*)d_ws;
    const size_t SZ = (size_t)BB * HH * SS * DK * sizeof(short); // 16 MB
    short* Qh = (short*)(ws);
    short* Kh = (short*)(ws + SZ);
    short* Vh = (short*)(ws + 2 * SZ);
    short* Vt = (short*)(ws + 3 * SZ);
    short* Wt = (short*)(ws + 4 * SZ);                    // 6 MB
    const size_t XOFF = 4 * SZ + 3 * (size_t)DD * DD * sizeof(short); // 70 MB
    short* Xbf = (short*)(ws + XOFF);                     // 48 MB (optional)
    const size_t need = XOFF + 3 * (size_t)MM * DD * sizeof(short);

    wtrans_kernel<<<dim3(32, 32, 3), 256, 0, stream>>>(wq, wk, wv, Wt);
    if (ws_size >= need) {
        xcast_kernel<<<dim3(MM * DD / (256 * 8), 3), 256, 0, stream>>>(q, k, v, Xbf);
        qkvproj_kernel<1><<<dim3(8, 64, 3), 256, 0, stream>>>(q, k, v, Xbf, Wt, bq, bk, bv, Qh, Kh, Vh);
    } else {
        qkvproj_kernel<0><<<dim3(8, 64, 3), 256, 0, stream>>>(q, k, v, nullptr, Wt, bq, bk, bv, Qh, Kh, Vh);
    }
    vtrans_kernel<<<dim3(16, 128), 256, 0, stream>>>(Vh, Vt);
    attn_kernel<<<dim3(16, 128), 256, 0, stream>>>(Qh, Kh, Vt, out);
}